// Round 3
// baseline (6529.601 us; speedup 1.0000x reference)
//
#include <hip/hip_runtime.h>
#include <stdint.h>
#include <math.h>

// Autoregressive LSTM controller. B=4096, EMB=128, HID=512, OUT=64, STEPS=20.
// Round 3: gates GEMM on MFMA via 4-term bf16 hi/lo split (error ~2^-18).
//  - W_hh and h stored frag-major [tile16][ktile8][16][8] bf16 hi/lo ->
//    MFMA fragments are single coalesced 16B loads, no LDS in the GEMM.
//  - Each wave: 16 rows x 64 units x all 4 gate sections -> LSTM update
//    fully lane-local (i,f,g,o in same lane/reg).
//  - grid (8 ub, 64 mb): XCD = linear%8 = ub -> per-XCD L2 keeps one W-slice.
//  - Sampling (threefry partitionable) and E-table unchanged from the
//    passing fp32 version.

#define B_SZ  4096
#define EMB   128
#define HID   512
#define NOUT  64
#define STEPS 20
#define G4    2048   // 4*HID

typedef __attribute__((ext_vector_type(8))) short bf16x8;
typedef __attribute__((ext_vector_type(4))) float f32x4;

#define HF_ELEMS ((size_t)B_SZ * HID)       // per hi/lo plane of h
#define WSECT    ((size_t)HID * HID)         // per-section W plane (512x512)
#define WLO_OFF  (4 * WSECT)                 // lo planes follow 4 hi planes

// ---------------- threefry2x32 ----------------
__device__ __forceinline__ void tf2x32(uint32_t k0, uint32_t k1,
                                       uint32_t x0, uint32_t x1,
                                       uint32_t& o0, uint32_t& o1) {
  const uint32_t ks2 = k0 ^ k1 ^ 0x1BD11BDAu;
#define TFR(r) { x0 += x1; x1 = (x1 << (r)) | (x1 >> (32 - (r))); x1 ^= x0; }
  x0 += k0; x1 += k1;
  TFR(13) TFR(15) TFR(26) TFR(6)
  x0 += k1;  x1 += ks2 + 1u;
  TFR(17) TFR(29) TFR(16) TFR(24)
  x0 += ks2; x1 += k0 + 2u;
  TFR(13) TFR(15) TFR(26) TFR(6)
  x0 += k0;  x1 += k1 + 3u;
  TFR(17) TFR(29) TFR(16) TFR(24)
  x0 += k1;  x1 += ks2 + 4u;
  TFR(13) TFR(15) TFR(26) TFR(6)
  x0 += ks2; x1 += k0 + 5u;
#undef TFR
  o0 = x0; o1 = x1;
}

// RNE split of fp32 into bf16 hi + bf16 lo
__device__ __forceinline__ void bf16split(float f, ushort& hi, ushort& lo) {
  uint32_t u = __float_as_uint(f);
  uint32_t r = u + 0x7fffu + ((u >> 16) & 1u);
  hi = (ushort)(r >> 16);
  float fh = __uint_as_float((r >> 16) << 16);
  float fl = f - fh;                       // exact (Sterbenz)
  uint32_t v = __float_as_uint(fl);
  uint32_t r2 = v + 0x7fffu + ((v >> 16) & 1u);
  lo = (ushort)(r2 >> 16);
}

// frag-major index: element (row,k) of a [R][K] matrix, K=512
__device__ __forceinline__ size_t fidx(int row, int k) {
  return ((size_t)(row >> 4) * 64 + (k >> 3)) * 128 + ((row & 15) << 3) + (k & 7);
}

// ---------------- E_proj = emb @ W_ih.T + b_ih + b_hh (fp32) ----------------
__global__ __launch_bounds__(256) void eproj_kernel(
    const float* __restrict__ emb, const float* __restrict__ W_ih,
    const float* __restrict__ b_ih, const float* __restrict__ b_hh,
    float* __restrict__ E) {
  const int t = blockIdx.x;  // token 0..63
  __shared__ float es[EMB];
  for (int k = threadIdx.x; k < EMB; k += blockDim.x) es[k] = emb[t * EMB + k];
  __syncthreads();
  for (int j = threadIdx.x; j < G4; j += blockDim.x) {
    const float* w = W_ih + (size_t)j * EMB;
    float acc = 0.f;
#pragma unroll 8
    for (int k = 0; k < EMB; k += 4) {
      float4 wv = *(const float4*)(w + k);
      acc += wv.x * es[k] + wv.y * es[k + 1] + wv.z * es[k + 2] + wv.w * es[k + 3];
    }
    E[(size_t)t * G4 + j] = acc + b_ih[j] + b_hh[j];
  }
}

// ---------------- W_hh -> frag-major bf16 hi/lo ----------------
// thread per (row, ktile8): 2048 rows x 64 ktiles
__global__ __launch_bounds__(256) void wprep_kernel(
    const float* __restrict__ W_hh, ushort* __restrict__ wf) {
  const int id = blockIdx.x * 256 + threadIdx.x;   // 512 blocks
  const int row = id >> 6;        // 0..2047
  const int kt  = id & 63;        // ktile
  const int s = row >> 9, unit = row & 511;
  const float* src = W_hh + (size_t)row * HID + kt * 8;
  ushort hi[8], lo[8];
#pragma unroll
  for (int j = 0; j < 8; ++j) bf16split(src[j], hi[j], lo[j]);
  const size_t dst = s * WSECT + fidx(unit, kt * 8);
#pragma unroll
  for (int j = 0; j < 8; ++j) {
    wf[dst + j] = hi[j];
    wf[WLO_OFF + dst + j] = lo[j];
  }
}

// ---------------- fused MFMA gates GEMM + LSTM cell ----------------
// grid (8 ub, 64 mb), 256 threads = 4 waves; wave w: rows m0+w*16..+16,
// units u0..u0+64, all 4 sections. 4-term bf16 split accumulated fp32.
__global__ __launch_bounds__(256) void lstm_step_mfma(
    const ushort* __restrict__ hf,    // [2][B][HID] frag-major (hi, lo)
    float*        __restrict__ c,     // [B][HID] fp32, in-place
    float*        __restrict__ h_out, // [B][HID] fp32 (for logits)
    ushort*       __restrict__ hf_out,// [2][B][HID] frag-major
    const ushort* __restrict__ wf,    // [2][4][HID][HID] frag-major
    const float*  __restrict__ E,     // [64][2048]
    const int*    __restrict__ tok)   // [B]
{
  const int tid = threadIdx.x;
  const int w = tid >> 6, l = tid & 63;
  const int lrow = l & 15, lk = l >> 4;
  const int m0 = blockIdx.y * 64 + w * 16;
  const int u0 = blockIdx.x * 64;

  f32x4 acc[4][4];  // [section][nf]
#pragma unroll
  for (int s = 0; s < 4; ++s)
#pragma unroll
    for (int nf = 0; nf < 4; ++nf) acc[s][nf] = (f32x4){0.f, 0.f, 0.f, 0.f};

  // lane base offsets (ushort elements); advance by 512 per k-chunk of 32
  const size_t aoff = (size_t)(m0 >> 4) * 8192 + lk * 128 + lrow * 8;
  const ushort* a_hi = hf + aoff;
  const ushort* a_lo = hf + HF_ELEMS + aoff;
  const size_t boff0 = (size_t)(u0 >> 4) * 8192 + lk * 128 + lrow * 8;

  for (int kc = 0; kc < 16; ++kc) {
    const bf16x8 Ah = *(const bf16x8*)(a_hi + kc * 512);
    const bf16x8 Al = *(const bf16x8*)(a_lo + kc * 512);
#pragma unroll
    for (int s = 0; s < 4; ++s) {
#pragma unroll
      for (int nf = 0; nf < 4; ++nf) {
        const ushort* bp = wf + s * WSECT + boff0 + (size_t)nf * 8192 + kc * 512;
        const bf16x8 Bh = *(const bf16x8*)bp;
        const bf16x8 Bl = *(const bf16x8*)(bp + WLO_OFF);
        acc[s][nf] = __builtin_amdgcn_mfma_f32_16x16x32_bf16(Ah, Bh, acc[s][nf], 0, 0, 0);
        acc[s][nf] = __builtin_amdgcn_mfma_f32_16x16x32_bf16(Al, Bh, acc[s][nf], 0, 0, 0);
        acc[s][nf] = __builtin_amdgcn_mfma_f32_16x16x32_bf16(Ah, Bl, acc[s][nf], 0, 0, 0);
        acc[s][nf] = __builtin_amdgcn_mfma_f32_16x16x32_bf16(Al, Bl, acc[s][nf], 0, 0, 0);
      }
    }
  }

  // epilogue: C frag layout col=lane&15, row=(lane>>4)*4+reg
#pragma unroll
  for (int r = 0; r < 4; ++r) {
    const int m = m0 + lk * 4 + r;
    const int t = tok[m];
    const float* Erow = E + (size_t)t * G4;
#pragma unroll
    for (int nf = 0; nf < 4; ++nf) {
      const int j = u0 + nf * 16 + lrow;
      const float gi = acc[0][nf][r] + Erow[j];
      const float gf = acc[1][nf][r] + Erow[HID + j];
      const float gg = acc[2][nf][r] + Erow[2 * HID + j];
      const float go = acc[3][nf][r] + Erow[3 * HID + j];
      const float si = 1.f / (1.f + expf(-gi));
      const float sf = 1.f / (1.f + expf(-gf));
      const float so = 1.f / (1.f + expf(-go));
      const size_t cidx = (size_t)m * HID + j;
      const float nc = sf * c[cidx] + si * tanhf(gg);
      const float h = so * tanhf(nc);
      c[cidx] = nc;
      h_out[cidx] = h;
      ushort hi, lo;
      bf16split(h, hi, lo);
      const size_t fo = fidx(m, j);
      hf_out[fo] = hi;
      hf_out[HF_ELEMS + fo] = lo;
    }
  }
}

// ---------------- logits + softmax + categorical sample ----------------
// block (64,4): 4 rows per block, one wave per row.
__global__ __launch_bounds__(256) void logits_kernel(
    const float* __restrict__ h,      // [B][HID]
    const float* __restrict__ W_lin,  // [64][512]
    const float* __restrict__ b_lin,  // [64]
    float* __restrict__ out,          // [B][STEPS][64]
    int* __restrict__ tok,            // [B]
    int step)
{
  const int ty = threadIdx.y;
  const int b = blockIdx.x * 4 + ty;
  const int o = threadIdx.x;
  __shared__ float hs[4][HID];
  {
    const float4* src = (const float4*)(h + (size_t)b * HID);
    float4 v0 = src[o * 2], v1 = src[o * 2 + 1];
    *(float4*)&hs[ty][o * 8] = v0;
    *(float4*)&hs[ty][o * 8 + 4] = v1;
  }
  __syncthreads();

  float acc = b_lin[o];
  const float* w = W_lin + (size_t)o * HID;
#pragma unroll 8
  for (int k = 0; k < HID; k += 4) {
    float4 wv = *(const float4*)(w + k);
    acc += wv.x * hs[ty][k] + wv.y * hs[ty][k + 1] + wv.z * hs[ty][k + 2] + wv.w * hs[ty][k + 3];
  }
  const float logit = acc;

  float m = logit;
#pragma unroll
  for (int d = 32; d; d >>= 1) m = fmaxf(m, __shfl_xor(m, d));
  float e = expf(logit - m);
  float ssum = e;
#pragma unroll
  for (int d = 32; d; d >>= 1) ssum += __shfl_xor(ssum, d);
  out[((size_t)b * STEPS + step) * NOUT + o] = e / ssum;

  uint32_t s0, s1;
  tf2x32(0u, 42u, 0u, (uint32_t)step, s0, s1);  // split(key(42))[step]
  uint32_t r0, r1;
  const uint32_t idx = (uint32_t)(b * NOUT + o);
  tf2x32(s0, s1, 0u, idx, r0, r1);
  const uint32_t bits = r0 ^ r1;
  float u = __uint_as_float((bits >> 9) | 0x3f800000u) - 1.0f;
  u = fmaxf(u, 1.17549435e-38f);
  const float gmb = -logf(-logf(u));

  float v = logit + gmb;
  int bi = o;
#pragma unroll
  for (int d = 32; d; d >>= 1) {
    float ov = __shfl_xor(v, d);
    int oi = __shfl_xor(bi, d);
    if (ov > v || (ov == v && oi < bi)) { v = ov; bi = oi; }
  }
  if (o == 0) tok[b] = bi;
}

// ---------------- host ----------------
extern "C" void kernel_launch(void* const* d_in, const int* in_sizes, int n_in,
                              void* d_out, int out_size, void* d_ws, size_t ws_size,
                              hipStream_t stream) {
  const int*   x     = (const int*)d_in[0];
  const float* emb   = (const float*)d_in[1];
  const float* W_ih  = (const float*)d_in[2];
  const float* W_hh  = (const float*)d_in[3];
  const float* b_ih  = (const float*)d_in[4];
  const float* b_hh  = (const float*)d_in[5];
  const float* W_lin = (const float*)d_in[6];
  const float* b_lin = (const float*)d_in[7];
  float* out = (float*)d_out;

  float*  E   = (float*)d_ws;                 // 64*2048 f32
  float*  c   = E + 64 * G4;                  // B*HID f32
  float*  hfp = c + (size_t)B_SZ * HID;       // B*HID f32
  ushort* hf0 = (ushort*)(hfp + (size_t)B_SZ * HID);  // 2*B*HID bf16
  ushort* hf1 = hf0 + 2 * HF_ELEMS;
  ushort* wf  = hf1 + 2 * HF_ELEMS;           // 2*4*HID*HID bf16
  int*    tok = (int*)(wf + 2 * 4 * WSECT);

  hipMemsetAsync(hf0, 0, 2 * HF_ELEMS * sizeof(ushort), stream);
  hipMemsetAsync(c, 0, (size_t)B_SZ * HID * sizeof(float), stream);

  eproj_kernel<<<64, 256, 0, stream>>>(emb, W_ih, b_ih, b_hh, E);
  wprep_kernel<<<512, 256, 0, stream>>>(W_hh, wf);

  const int* cur_tok = x;
  ushort* hfin = hf0;
  ushort* hfout = hf1;
  for (int t = 0; t < STEPS; ++t) {
    lstm_step_mfma<<<dim3(8, 64), 256, 0, stream>>>(hfin, c, hfp, hfout, wf, E, cur_tok);
    logits_kernel<<<B_SZ / 4, dim3(64, 4), 0, stream>>>(hfp, W_lin, b_lin, out, tok, t);
    cur_tok = tok;
    ushort* tmp = hfin; hfin = hfout; hfout = tmp;
  }
}

// Round 4
// 1586.816 us; speedup vs baseline: 4.1149x; 4.1149x over previous
//
#include <hip/hip_runtime.h>
#include <stdint.h>
#include <math.h>

// Autoregressive LSTM controller. B=4096, EMB=128, HID=512, OUT=64, STEPS=20.
// Round 4: LDS-staged MFMA GEMM (32x32x16 bf16, 4-term hi/lo split).
//  - W_hh pre-swizzled once into wswz so global_load_lds (linear dest) +
//    XOR-swizzled ds_read are conflict-free (rule-21 both-sides pattern).
//  - A (h) register-direct from frag-major layout; B (W) via 2-phase LDS
//    double-buffer: stage(t+1) -> compute(t) -> vmcnt(0)+barrier.
//  - Wave = 32 rows x 32 units x 4 sections -> gates i,f,g,o lane-local.
//  - Logits: W_lin transposed once to [k4][o][4] (coalesced), 8 rows/block.

#define B_SZ  4096
#define EMB   128
#define HID   512
#define NOUT  64
#define STEPS 20
#define G4    2048
#define HF    ((size_t)B_SZ * HID)   // elems per hi/lo plane of h

typedef __attribute__((ext_vector_type(8)))  short bf16x8;
typedef __attribute__((ext_vector_type(16))) float f32x16;

union B8 { uint2 q[2]; bf16x8 v; };

// ---------------- threefry2x32 (JAX partitionable semantics) ----------------
__device__ __forceinline__ void tf2x32(uint32_t k0, uint32_t k1,
                                       uint32_t x0, uint32_t x1,
                                       uint32_t& o0, uint32_t& o1) {
  const uint32_t ks2 = k0 ^ k1 ^ 0x1BD11BDAu;
#define TFR(r) { x0 += x1; x1 = (x1 << (r)) | (x1 >> (32 - (r))); x1 ^= x0; }
  x0 += k0; x1 += k1;
  TFR(13) TFR(15) TFR(26) TFR(6)
  x0 += k1;  x1 += ks2 + 1u;
  TFR(17) TFR(29) TFR(16) TFR(24)
  x0 += ks2; x1 += k0 + 2u;
  TFR(13) TFR(15) TFR(26) TFR(6)
  x0 += k0;  x1 += k1 + 3u;
  TFR(17) TFR(29) TFR(16) TFR(24)
  x0 += k1;  x1 += ks2 + 4u;
  TFR(13) TFR(15) TFR(26) TFR(6)
  x0 += ks2; x1 += k0 + 5u;
#undef TFR
  o0 = x0; o1 = x1;
}

// RNE split of fp32 into bf16 hi + bf16 lo
__device__ __forceinline__ void bf16split(float f, ushort& hi, ushort& lo) {
  uint32_t u = __float_as_uint(f);
  uint32_t r = u + 0x7fffu + ((u >> 16) & 1u);
  hi = (ushort)(r >> 16);
  float fh = __uint_as_float((r >> 16) << 16);
  float fl = f - fh;
  uint32_t v = __float_as_uint(fl);
  uint32_t r2 = v + 0x7fffu + ((v >> 16) & 1u);
  lo = (ushort)(r2 >> 16);
}

__device__ __forceinline__ void gload_lds16(const ushort* g, ushort* d) {
  __builtin_amdgcn_global_load_lds(
      (const __attribute__((address_space(1))) void*)g,
      (__attribute__((address_space(3))) void*)d, 16, 0, 0);
}

// ---------------- E_proj = emb @ W_ih.T + b_ih + b_hh (fp32, once) ----------
__global__ __launch_bounds__(256) void eproj_kernel(
    const float* __restrict__ emb, const float* __restrict__ W_ih,
    const float* __restrict__ b_ih, const float* __restrict__ b_hh,
    float* __restrict__ E) {
  const int t = blockIdx.x;
  __shared__ float es[EMB];
  for (int k = threadIdx.x; k < EMB; k += blockDim.x) es[k] = emb[t * EMB + k];
  __syncthreads();
  for (int j = threadIdx.x; j < G4; j += blockDim.x) {
    const float* w = W_ih + (size_t)j * EMB;
    float acc = 0.f;
#pragma unroll 8
    for (int k = 0; k < EMB; k += 4) {
      float4 wv = *(const float4*)(w + k);
      acc += wv.x * es[k] + wv.y * es[k + 1] + wv.z * es[k + 2] + wv.w * es[k + 3];
    }
    E[(size_t)t * G4 + j] = acc + b_ih[j] + b_hh[j];
  }
}

// ---------------- W_hh -> pre-swizzled staging mirror (once) ----------------
// wswz[ub][plane][kt][row][e]; row in [0,128): section=row>>5, unit=ub*32+(row&31)
// element e holds W[grow][kt*64 + (e ^ ((row&15)<<2))]  (8B-granular XOR swizzle)
__global__ __launch_bounds__(256) void wprep_whh(
    const float* __restrict__ W_hh, ushort* __restrict__ wswz) {
  const int id = blockIdx.x * 256 + threadIdx.x;   // 1024 blocks -> 262144 chunks
  const int ub    = id >> 14;
  const int plane = (id >> 13) & 1;
  const int kt    = (id >> 10) & 7;
  const int row   = (id >> 3) & 127;
  const int ec    = id & 7;
  const int grow = (row >> 5) * HID + ub * 32 + (row & 31);
  const int swz = (row & 15) << 2;
  ushort vals[8];
#pragma unroll
  for (int j = 0; j < 8; ++j) {
    const int e = ec * 8 + j;
    const int k = kt * 64 + (e ^ swz);
    ushort hi, lo;
    bf16split(W_hh[(size_t)grow * HID + k], hi, lo);
    vals[j] = plane ? lo : hi;
  }
  *(uint4*)(wswz + (size_t)id * 8) = *(const uint4*)vals;
}

// ---------------- W_lin -> coalesced transpose [k4][o][4] (once) ------------
__global__ __launch_bounds__(256) void wprep_lin(
    const float* __restrict__ W_lin, float* __restrict__ wlt) {
  const int id = blockIdx.x * 256 + threadIdx.x;   // 128 blocks -> 32768
  const int j = id & 3, o = (id >> 2) & 63, k4 = id >> 8;
  wlt[id] = W_lin[(size_t)o * HID + k4 * 4 + j];
}

// ---------------- fused MFMA gates GEMM + LSTM cell ----------------
// grid (16 ub, 16 mb), 512 thr = 8 waves; wave = 32 rows x 32 units x 4 sect.
__global__ __launch_bounds__(512) void lstm_step_mfma(
    const ushort* __restrict__ hf,     // [2][frag-major B x HID]
    float*        __restrict__ c,      // [B][HID] fp32 in-place
    float*        __restrict__ h_out,  // [B][HID] fp32 (logits input)
    ushort*       __restrict__ hf_out, // [2][frag-major]
    const ushort* __restrict__ wswz,   // pre-swizzled W mirror
    const float*  __restrict__ E,      // [64][2048]
    const int*    __restrict__ tok)    // [B]
{
  __shared__ ushort Bt[2][8192];       // 2 x 16 KB double buffer
  const int tid = threadIdx.x;
  const int w = tid >> 6, l = tid & 63;
  const int l31 = l & 31, lh = l >> 5;
  const int ub = blockIdx.x, mb = blockIdx.y;
  const int m0 = mb * 256 + w * 32;
  const int u0 = ub * 32;

  f32x16 acc[4] = {};

  // A (h) frag-major base: rows m0+(l&31), k-half lh
  const size_t abase = ((size_t)(m0 >> 5) * 64 + lh) * 256 + (size_t)l31 * 8;
  const ushort* a0 = hf + abase;
  const ushort* a1 = hf + HF + abase;

  const ushort* wbase = wswz + (size_t)ub * 131072;

  // prologue: stage tile 0
  {
    const ushort* src = wbase + w * 1024 + l * 8;
    ushort* dst = &Bt[0][w * 1024];
    gload_lds16(src, dst);
    gload_lds16(src + 512, dst + 512);
  }
  asm volatile("s_waitcnt vmcnt(0)" ::: "memory");
  __syncthreads();

  int buf = 0;
  for (int t = 0; t < 16; ++t) {        // t = plane*8 + kt
    const int kt = t & 7;
    if (t < 15) {
      const ushort* src = wbase + (size_t)(t + 1) * 8192 + w * 1024 + l * 8;
      ushort* dst = &Bt[buf ^ 1][w * 1024];
      gload_lds16(src, dst);
      gload_lds16(src + 512, dst + 512);
    }
    bf16x8 A0[4], A1[4];
#pragma unroll
    for (int kc = 0; kc < 4; ++kc) {
      const size_t koff = (size_t)(kt * 8 + kc * 2) * 256;
      A0[kc] = *(const bf16x8*)(a0 + koff);
      A1[kc] = *(const bf16x8*)(a1 + koff);
    }
#pragma unroll
    for (int kc = 0; kc < 4; ++kc) {
      const int eb = kc * 16 + lh * 8;
#pragma unroll
      for (int s = 0; s < 4; ++s) {
        const int row = s * 32 + l31;
        const int swz = (row & 15) << 2;
        const ushort* rb = &Bt[buf][row * 64];
        B8 u;
        u.q[0] = *(const uint2*)(rb + ((eb)     ^ swz));
        u.q[1] = *(const uint2*)(rb + ((eb + 4) ^ swz));
        acc[s] = __builtin_amdgcn_mfma_f32_32x32x16_bf16(A0[kc], u.v, acc[s], 0, 0, 0);
        acc[s] = __builtin_amdgcn_mfma_f32_32x32x16_bf16(A1[kc], u.v, acc[s], 0, 0, 0);
      }
    }
    asm volatile("s_waitcnt vmcnt(0)" ::: "memory");
    __syncthreads();
    buf ^= 1;
  }

  // epilogue: C layout col=l31 (unit), row=(r&3)+8*(r>>2)+4*lh
  const int u = u0 + l31;
#pragma unroll
  for (int r = 0; r < 16; ++r) {
    const int m = m0 + (r & 3) + 8 * (r >> 2) + 4 * lh;
    const int tk = tok[m];
    const float* Erow = E + (size_t)tk * G4;
    const float gi = acc[0][r] + Erow[u];
    const float gf = acc[1][r] + Erow[HID + u];
    const float gg = acc[2][r] + Erow[2 * HID + u];
    const float go = acc[3][r] + Erow[3 * HID + u];
    const float si = 1.f / (1.f + expf(-gi));
    const float sf = 1.f / (1.f + expf(-gf));
    const float so = 1.f / (1.f + expf(-go));
    const size_t ci = (size_t)m * HID + u;
    const float nc = sf * c[ci] + si * tanhf(gg);
    const float hv = so * tanhf(nc);
    c[ci] = nc;
    h_out[ci] = hv;
    ushort hi, lo;
    bf16split(hv, hi, lo);
    const size_t fo = ((size_t)(m >> 5) * 64 + (u >> 3)) * 256 + (size_t)(m & 31) * 8 + (u & 7);
    hf_out[fo] = hi;
    hf_out[HF + fo] = lo;
  }
}

// ---------------- logits + softmax + categorical sample ----------------
// 512 blocks x 256 thr; wave rg handles rows b0..b0+1 (8 rows/block).
__global__ __launch_bounds__(256) void logits2(
    const float* __restrict__ h, const float* __restrict__ wlt,
    const float* __restrict__ b_lin, float* __restrict__ out,
    int* __restrict__ tok, int step)
{
  const int tid = threadIdx.x;
  const int o = tid & 63;
  const int rg = tid >> 6;
  const int b0 = blockIdx.x * 8 + rg * 2;
  float acc0 = 0.f, acc1 = 0.f;
  const float* h0 = h + (size_t)b0 * HID;
  const float* h1 = h0 + HID;
#pragma unroll 4
  for (int k4 = 0; k4 < 128; ++k4) {
    const float4 wv = *(const float4*)(wlt + (size_t)(k4 * 64 + o) * 4);
    const float4 x0 = *(const float4*)(h0 + k4 * 4);
    const float4 x1 = *(const float4*)(h1 + k4 * 4);
    acc0 += wv.x * x0.x + wv.y * x0.y + wv.z * x0.z + wv.w * x0.w;
    acc1 += wv.x * x1.x + wv.y * x1.y + wv.z * x1.z + wv.w * x1.w;
  }
  const float bl = b_lin[o];
  uint32_t s0, s1;
  tf2x32(0u, 42u, 0u, (uint32_t)step, s0, s1);
  float lg[2] = {acc0 + bl, acc1 + bl};
#pragma unroll
  for (int r = 0; r < 2; ++r) {
    const int b = b0 + r;
    const float logit = lg[r];
    float mx = logit;
#pragma unroll
    for (int d = 32; d; d >>= 1) mx = fmaxf(mx, __shfl_xor(mx, d));
    float e = expf(logit - mx);
    float ssum = e;
#pragma unroll
    for (int d = 32; d; d >>= 1) ssum += __shfl_xor(ssum, d);
    out[((size_t)b * STEPS + step) * NOUT + o] = e / ssum;

    uint32_t r0, r1;
    tf2x32(s0, s1, 0u, (uint32_t)(b * NOUT + o), r0, r1);
    const uint32_t bits = r0 ^ r1;
    float uu = __uint_as_float((bits >> 9) | 0x3f800000u) - 1.0f;
    uu = fmaxf(uu, 1.17549435e-38f);
    const float gmb = -logf(-logf(uu));
    float v = logit + gmb;
    int bi = o;
#pragma unroll
    for (int d = 32; d; d >>= 1) {
      float ov = __shfl_xor(v, d);
      int oi = __shfl_xor(bi, d);
      if (ov > v || (ov == v && oi < bi)) { v = ov; bi = oi; }
    }
    if (o == 0) tok[b] = bi;
  }
}

// ---------------- host ----------------
extern "C" void kernel_launch(void* const* d_in, const int* in_sizes, int n_in,
                              void* d_out, int out_size, void* d_ws, size_t ws_size,
                              hipStream_t stream) {
  const int*   x     = (const int*)d_in[0];
  const float* emb   = (const float*)d_in[1];
  const float* W_ih  = (const float*)d_in[2];
  const float* W_hh  = (const float*)d_in[3];
  const float* b_ih  = (const float*)d_in[4];
  const float* b_hh  = (const float*)d_in[5];
  const float* W_lin = (const float*)d_in[6];
  const float* b_lin = (const float*)d_in[7];
  float* out = (float*)d_out;

  float*  E    = (float*)d_ws;              // 131072 f32
  float*  c    = E + 131072;                // 2M f32
  float*  h    = c + HF;                    // 2M f32
  float*  wlt  = h + HF;                    // 32768 f32
  ushort* hf0  = (ushort*)(wlt + 32768);    // 2 planes x 2M u16
  ushort* hf1  = hf0 + 2 * HF;
  ushort* wswz = hf1 + 2 * HF;              // 2M u16
  int*    tok  = (int*)(wswz + 2097152);

  hipMemsetAsync(hf0, 0, 2 * HF * sizeof(ushort), stream);
  hipMemsetAsync(c, 0, HF * sizeof(float), stream);

  eproj_kernel<<<64, 256, 0, stream>>>(emb, W_ih, b_ih, b_hh, E);
  wprep_whh<<<1024, 256, 0, stream>>>(W_hh, wswz);
  wprep_lin<<<128, 256, 0, stream>>>(W_lin, wlt);

  const int* cur_tok = x;
  ushort* hfin = hf0;
  ushort* hfout = hf1;
  for (int t = 0; t < STEPS; ++t) {
    lstm_step_mfma<<<dim3(16, 16), 512, 0, stream>>>(hfin, c, h, hfout, wswz, E, cur_tok);
    logits2<<<512, 256, 0, stream>>>(h, wlt, b_lin, out, tok, t);
    cur_tok = tok;
    ushort* tmp = hfin; hfin = hfout; hfout = tmp;
  }
}

// Round 5
// 1317.622 us; speedup vs baseline: 4.9556x; 1.2043x over previous
//
#include <hip/hip_runtime.h>
#include <stdint.h>
#include <math.h>

// Autoregressive LSTM controller. B=4096, EMB=128, HID=512, OUT=64, STEPS=20.
// Round 5: 3-term bf16 split (drop Al*Bl), 8-phase-per-step K loop staging
// both hi/lo W planes per tile (halves barriers + A traffic), 16B-granule
// LDS swizzle (ds_read_b128), XCD-aware 2x4 group swizzle of (ub,mb),
// grid 512 x 256thr (2 blocks/CU for barrier overlap).

#define B_SZ  4096
#define EMB   128
#define HID   512
#define NOUT  64
#define STEPS 20
#define G4    2048
#define HF    ((size_t)B_SZ * HID)   // elems per hi/lo plane of h

typedef __attribute__((ext_vector_type(8)))  short bf16x8;
typedef __attribute__((ext_vector_type(16))) float f32x16;

// ---------------- threefry2x32 (JAX partitionable semantics) ----------------
__device__ __forceinline__ void tf2x32(uint32_t k0, uint32_t k1,
                                       uint32_t x0, uint32_t x1,
                                       uint32_t& o0, uint32_t& o1) {
  const uint32_t ks2 = k0 ^ k1 ^ 0x1BD11BDAu;
#define TFR(r) { x0 += x1; x1 = (x1 << (r)) | (x1 >> (32 - (r))); x1 ^= x0; }
  x0 += k0; x1 += k1;
  TFR(13) TFR(15) TFR(26) TFR(6)
  x0 += k1;  x1 += ks2 + 1u;
  TFR(17) TFR(29) TFR(16) TFR(24)
  x0 += ks2; x1 += k0 + 2u;
  TFR(13) TFR(15) TFR(26) TFR(6)
  x0 += k0;  x1 += k1 + 3u;
  TFR(17) TFR(29) TFR(16) TFR(24)
  x0 += k1;  x1 += ks2 + 4u;
  TFR(13) TFR(15) TFR(26) TFR(6)
  x0 += ks2; x1 += k0 + 5u;
#undef TFR
  o0 = x0; o1 = x1;
}

// RNE split of fp32 into bf16 hi + bf16 lo
__device__ __forceinline__ void bf16split(float f, ushort& hi, ushort& lo) {
  uint32_t u = __float_as_uint(f);
  uint32_t r = u + 0x7fffu + ((u >> 16) & 1u);
  hi = (ushort)(r >> 16);
  float fh = __uint_as_float((r >> 16) << 16);
  float fl = f - fh;
  uint32_t v = __float_as_uint(fl);
  uint32_t r2 = v + 0x7fffu + ((v >> 16) & 1u);
  lo = (ushort)(r2 >> 16);
}

__device__ __forceinline__ void gload_lds16(const ushort* g, ushort* d) {
  __builtin_amdgcn_global_load_lds(
      (const __attribute__((address_space(1))) void*)g,
      (__attribute__((address_space(3))) void*)d, 16, 0, 0);
}

// ---------------- E_proj = emb @ W_ih.T + b_ih + b_hh (fp32, once) ----------
__global__ __launch_bounds__(256) void eproj_kernel(
    const float* __restrict__ emb, const float* __restrict__ W_ih,
    const float* __restrict__ b_ih, const float* __restrict__ b_hh,
    float* __restrict__ E) {
  const int t = blockIdx.x;
  __shared__ float es[EMB];
  for (int k = threadIdx.x; k < EMB; k += blockDim.x) es[k] = emb[t * EMB + k];
  __syncthreads();
  for (int j = threadIdx.x; j < G4; j += blockDim.x) {
    const float* w = W_ih + (size_t)j * EMB;
    float acc = 0.f;
#pragma unroll 8
    for (int k = 0; k < EMB; k += 4) {
      float4 wv = *(const float4*)(w + k);
      acc += wv.x * es[k] + wv.y * es[k + 1] + wv.z * es[k + 2] + wv.w * es[k + 3];
    }
    E[(size_t)t * G4 + j] = acc + b_ih[j] + b_hh[j];
  }
}

// ---------------- W_hh -> pre-swizzled staging mirror (once) ----------------
// Layout: [ub(16)][kt(8)][plane(2)][row(128)][e(64)], e XOR-swizzled at
// 8-elem (16B) granule: position e holds W[grow][kt*64 + (e ^ ((row&7)<<3))].
// row: section = row>>5, unit = ub*32 + (row&31).
__global__ __launch_bounds__(256) void wprep_whh(
    const float* __restrict__ W_hh, ushort* __restrict__ wswz) {
  const int id = blockIdx.x * 256 + threadIdx.x;   // 1024 blocks -> 262144 chunks
  const int ub    = id >> 14;
  const int w14   = id & 16383;
  const int kt    = w14 >> 11;
  const int plane = (w14 >> 10) & 1;
  const int row   = (w14 >> 3) & 127;
  const int ec    = w14 & 7;
  const int grow = (row >> 5) * HID + ub * 32 + (row & 31);
  const int swz = (row & 7) << 3;
  ushort vals[8];
#pragma unroll
  for (int j = 0; j < 8; ++j) {
    const int e = ec * 8 + j;
    const int k = kt * 64 + (e ^ swz);
    ushort hi, lo;
    bf16split(W_hh[(size_t)grow * HID + k], hi, lo);
    vals[j] = plane ? lo : hi;
  }
  *(uint4*)(wswz + (size_t)id * 8) = *(const uint4*)vals;
}

// ---------------- W_lin -> coalesced transpose [k4][o][4] (once) ------------
__global__ __launch_bounds__(256) void wprep_lin(
    const float* __restrict__ W_lin, float* __restrict__ wlt) {
  const int id = blockIdx.x * 256 + threadIdx.x;   // 128 blocks -> 32768
  const int j = id & 3, o = (id >> 2) & 63, k4 = id >> 8;
  wlt[id] = W_lin[(size_t)o * HID + k4 * 4 + j];
}

// ---------------- fused MFMA gates GEMM + LSTM cell ----------------
// 512 blocks x 256 thr (4 waves); wave = 32 rows x 32 units x 4 sections.
// XCD swizzle: raw&7 -> (g_ub, g_mb); each XCD owns 8 ub x 8 mb tiles.
__global__ __launch_bounds__(256, 2) void lstm_step_mfma(
    const ushort* __restrict__ hf,     // [2][frag-major B x HID]
    float*        __restrict__ c,      // [B][HID] fp32 in-place
    float*        __restrict__ h_out,  // [B][HID] fp32 (logits input)
    ushort*       __restrict__ hf_out, // [2][frag-major]
    const ushort* __restrict__ wswz,   // pre-swizzled W mirror
    const float*  __restrict__ E,      // [64][2048]
    const int*    __restrict__ tok)    // [B]
{
  __shared__ ushort Bt[2][16384];      // 2 x 32 KB double buffer (both planes)
  const int tid = threadIdx.x;
  const int w = tid >> 6, l = tid & 63;
  const int l31 = l & 31, lh = l >> 5;

  // XCD-aware decode: linear%8 = XCD; group = (ub>>3, mb>>3)
  const int raw = blockIdx.x;
  const int x = raw & 7, j = raw >> 3;
  const int ub  = (x & 1) * 8 + (j & 7);
  const int mbi = (x >> 1) * 8 + (j >> 3);
  const int m0 = mbi * 128 + w * 32;
  const int u0 = ub * 32;

  f32x16 acc[4] = {};

  // A (h) frag-major base: rows m0+(l&31), k-half lh
  const size_t abase = ((size_t)(m0 >> 5) * 64 + lh) * 256 + (size_t)l31 * 8;
  const ushort* a0 = hf + abase;
  const ushort* a1 = hf + HF + abase;

  const ushort* wbase = wswz + (size_t)ub * 131072;

  // prologue: stage kt=0 tile (32 KB, both planes)
  {
    const ushort* src = wbase + (size_t)(w * 64 + l) * 8;
    ushort* dst = &Bt[0][w * 512];
#pragma unroll
    for (int r = 0; r < 8; ++r)
      gload_lds16(src + r * 2048, dst + r * 2048);
  }
  asm volatile("s_waitcnt vmcnt(0)" ::: "memory");
  __syncthreads();

  int buf = 0;
  for (int kt = 0; kt < 8; ++kt) {
    if (kt < 7) {
      const ushort* src = wbase + (size_t)(kt + 1) * 16384 + (size_t)(w * 64 + l) * 8;
      ushort* dst = &Bt[buf ^ 1][w * 512];
#pragma unroll
      for (int r = 0; r < 8; ++r)
        gload_lds16(src + r * 2048, dst + r * 2048);
    }
    bf16x8 A0[4], A1[4];
#pragma unroll
    for (int kc = 0; kc < 4; ++kc) {
      const size_t koff = (size_t)(kt * 8 + kc * 2) * 256;
      A0[kc] = *(const bf16x8*)(a0 + koff);
      A1[kc] = *(const bf16x8*)(a1 + koff);
    }
#pragma unroll
    for (int kc = 0; kc < 4; ++kc) {
#pragma unroll
      for (int s = 0; s < 4; ++s) {
        const int row = s * 32 + l31;
        const int phys = (((kc * 2 + lh) ^ (row & 7)) << 3);
        const ushort* rb = &Bt[buf][row * 64 + phys];
        const bf16x8 Bh = *(const bf16x8*)rb;
        const bf16x8 Bl = *(const bf16x8*)(rb + 8192);
        acc[s] = __builtin_amdgcn_mfma_f32_32x32x16_bf16(A0[kc], Bh, acc[s], 0, 0, 0);
        acc[s] = __builtin_amdgcn_mfma_f32_32x32x16_bf16(A1[kc], Bh, acc[s], 0, 0, 0);
        acc[s] = __builtin_amdgcn_mfma_f32_32x32x16_bf16(A0[kc], Bl, acc[s], 0, 0, 0);
      }
    }
    asm volatile("s_waitcnt vmcnt(0)" ::: "memory");
    __syncthreads();
    buf ^= 1;
  }

  // epilogue: C layout col=l31 (unit), row=(r&3)+8*(r>>2)+4*lh
  const int u = u0 + l31;
#pragma unroll
  for (int r = 0; r < 16; ++r) {
    const int m = m0 + (r & 3) + 8 * (r >> 2) + 4 * lh;
    const int tk = tok[m];
    const float* Erow = E + (size_t)tk * G4;
    const float gi = acc[0][r] + Erow[u];
    const float gf = acc[1][r] + Erow[HID + u];
    const float gg = acc[2][r] + Erow[2 * HID + u];
    const float go = acc[3][r] + Erow[3 * HID + u];
    const float si = 1.f / (1.f + expf(-gi));
    const float sf = 1.f / (1.f + expf(-gf));
    const float so = 1.f / (1.f + expf(-go));
    const size_t ci = (size_t)m * HID + u;
    const float nc = sf * c[ci] + si * tanhf(gg);
    const float hv = so * tanhf(nc);
    c[ci] = nc;
    h_out[ci] = hv;
    ushort hi, lo;
    bf16split(hv, hi, lo);
    const size_t fo = ((size_t)(m >> 5) * 64 + (u >> 3)) * 256 + (size_t)(m & 31) * 8 + (u & 7);
    hf_out[fo] = hi;
    hf_out[HF + fo] = lo;
  }
}

// ---------------- logits + softmax + categorical sample ----------------
// 512 blocks x 256 thr; wave rg handles rows b0..b0+1 (8 rows/block).
__global__ __launch_bounds__(256) void logits2(
    const float* __restrict__ h, const float* __restrict__ wlt,
    const float* __restrict__ b_lin, float* __restrict__ out,
    int* __restrict__ tok, int step)
{
  const int tid = threadIdx.x;
  const int o = tid & 63;
  const int rg = tid >> 6;
  const int b0 = blockIdx.x * 8 + rg * 2;
  float acc0 = 0.f, acc1 = 0.f;
  const float* h0 = h + (size_t)b0 * HID;
  const float* h1 = h0 + HID;
#pragma unroll 4
  for (int k4 = 0; k4 < 128; ++k4) {
    const float4 wv = *(const float4*)(wlt + (size_t)(k4 * 64 + o) * 4);
    const float4 x0 = *(const float4*)(h0 + k4 * 4);
    const float4 x1 = *(const float4*)(h1 + k4 * 4);
    acc0 += wv.x * x0.x + wv.y * x0.y + wv.z * x0.z + wv.w * x0.w;
    acc1 += wv.x * x1.x + wv.y * x1.y + wv.z * x1.z + wv.w * x1.w;
  }
  const float bl = b_lin[o];
  uint32_t s0, s1;
  tf2x32(0u, 42u, 0u, (uint32_t)step, s0, s1);
  float lg[2] = {acc0 + bl, acc1 + bl};
#pragma unroll
  for (int r = 0; r < 2; ++r) {
    const int b = b0 + r;
    const float logit = lg[r];
    float mx = logit;
#pragma unroll
    for (int d = 32; d; d >>= 1) mx = fmaxf(mx, __shfl_xor(mx, d));
    float e = expf(logit - mx);
    float ssum = e;
#pragma unroll
    for (int d = 32; d; d >>= 1) ssum += __shfl_xor(ssum, d);
    out[((size_t)b * STEPS + step) * NOUT + o] = e / ssum;

    uint32_t r0, r1;
    tf2x32(s0, s1, 0u, (uint32_t)(b * NOUT + o), r0, r1);
    const uint32_t bits = r0 ^ r1;
    float uu = __uint_as_float((bits >> 9) | 0x3f800000u) - 1.0f;
    uu = fmaxf(uu, 1.17549435e-38f);
    const float gmb = -logf(-logf(uu));
    float v = logit + gmb;
    int bi = o;
#pragma unroll
    for (int d = 32; d; d >>= 1) {
      float ov = __shfl_xor(v, d);
      int oi = __shfl_xor(bi, d);
      if (ov > v || (ov == v && oi < bi)) { v = ov; bi = oi; }
    }
    if (o == 0) tok[b] = bi;
  }
}

// ---------------- host ----------------
extern "C" void kernel_launch(void* const* d_in, const int* in_sizes, int n_in,
                              void* d_out, int out_size, void* d_ws, size_t ws_size,
                              hipStream_t stream) {
  const int*   x     = (const int*)d_in[0];
  const float* emb   = (const float*)d_in[1];
  const float* W_ih  = (const float*)d_in[2];
  const float* W_hh  = (const float*)d_in[3];
  const float* b_ih  = (const float*)d_in[4];
  const float* b_hh  = (const float*)d_in[5];
  const float* W_lin = (const float*)d_in[6];
  const float* b_lin = (const float*)d_in[7];
  float* out = (float*)d_out;

  float*  E    = (float*)d_ws;              // 131072 f32
  float*  c    = E + 131072;                // 2M f32
  float*  h    = c + HF;                    // 2M f32
  float*  wlt  = h + HF;                    // 32768 f32
  ushort* hf0  = (ushort*)(wlt + 32768);    // 2 planes x 2M u16
  ushort* hf1  = hf0 + 2 * HF;
  ushort* wswz = hf1 + 2 * HF;              // 2M u16
  int*    tok  = (int*)(wswz + 2097152);

  hipMemsetAsync(hf0, 0, 2 * HF * sizeof(ushort), stream);
  hipMemsetAsync(c, 0, HF * sizeof(float), stream);

  eproj_kernel<<<64, 256, 0, stream>>>(emb, W_ih, b_ih, b_hh, E);
  wprep_whh<<<1024, 256, 0, stream>>>(W_hh, wswz);
  wprep_lin<<<128, 256, 0, stream>>>(W_lin, wlt);

  const int* cur_tok = x;
  ushort* hfin = hf0;
  ushort* hfout = hf1;
  for (int t = 0; t < STEPS; ++t) {
    lstm_step_mfma<<<512, 256, 0, stream>>>(hfin, c, h, hfout, wswz, E, cur_tok);
    logits2<<<512, 256, 0, stream>>>(h, wlt, b_lin, out, tok, t);
    cur_tok = tok;
    ushort* tmp = hfin; hfin = hfout; hfout = tmp;
  }
}